// Round 1
// baseline (781.262 us; speedup 1.0000x reference)
//
#include <hip/hip_runtime.h>
#include <hip/hip_bf16.h>
#include <math.h>

// FlowMatchingLoss: B=8, M=K=2048. All log-domain values are pre-scaled by
// log2(e) so hardware exp2/log2 (v_exp_f32 / v_log_f32) apply directly.
//   K_log' = sc_b * max(c,0),  sc_b = -20*log2e/(cmax_b+1e-8)
//   lse'(x_i) = log2 sum exp2(x_i)   (consistent base-2 logsumexp)

#define LOG2E 1.4426950408889634f
#define TAU   0.95238095238095238f     // 1.0/(1.0+0.05)
#define NEG20LOG2E (-28.853900817779268f)

// workspace layout, in 4-byte units
enum : int {
  OFF_PA4  = 0,        // B*M float4: x0.xyz, |x0|^2
  OFF_PB4  = 65536,    // B*K float4: xgt.xyz, |xgt|^2
  OFF_A    = 131072,   // a = sigmoid(10*tanh(alpha/10))
  OFF_LA2  = 147456,   // log2(max(a,1e-30))
  OFF_LU   = 163840,   // log_u * log2e
  OFF_LV   = 180224,   // log_v * log2e  (zeroed region starts here)
  OFF_XHI  = 196608,   // 96 uints: ordered-encoded max of lu/lv per pass,batch
  OFF_CMAX = 196704,   // 8 uints: per-batch cost max (bits of nonneg float)
  OFF_SUMA = 196712,   // 8: per-batch sum of a
  OFF_SC   = 196720,   // 8: per-batch K_log' scale
  OFF_LB2  = 196728,   // 8: log2(b)
  OFF_SCAL = 196736,   // 8: [0]=sum_w [1]=sum_w*err [2]=bce [3]=sum_pi [4]=sum_pi*kl'
  OFF_END  = 196744
};

__device__ __forceinline__ float fexp2(float x){ return __builtin_amdgcn_exp2f(x); }
__device__ __forceinline__ float flog2(float x){ return __builtin_amdgcn_logf(x); }

// monotonic float<->uint encoding for atomicMax over signed floats; init 0 < all
__device__ __forceinline__ unsigned enc_ord(float f){
  unsigned u = __float_as_uint(f);
  return (u & 0x80000000u) ? ~u : (u | 0x80000000u);
}
__device__ __forceinline__ float dec_ord(unsigned u){
  unsigned b = (u & 0x80000000u) ? (u ^ 0x80000000u) : ~u;
  return __uint_as_float(b);
}

__device__ __forceinline__ float wave_sum(float v){
  #pragma unroll
  for(int m=32;m;m>>=1) v += __shfl_xor(v,m,64);
  return v;
}
__device__ __forceinline__ float wave_max(float v){
  #pragma unroll
  for(int m=32;m;m>>=1) v = fmaxf(v,__shfl_xor(v,m,64));
  return v;
}

// ---------- prep: pack points+norms, a/log_a, velocity-loss sums ----------
__global__ __launch_bounds__(256) void k_prep(const float* __restrict__ x0,
                                              const float* __restrict__ xgt,
                                              const float* __restrict__ vp,
                                              const float* __restrict__ ap,
                                              const float* __restrict__ mxp,
                                              float* __restrict__ ws){
  const int idx = blockIdx.x*256 + threadIdx.x;   // block lies in one batch
  const int b = idx >> 11;
  const float x = x0[idx*3], y = x0[idx*3+1], z = x0[idx*3+2];
  reinterpret_cast<float4*>(ws+OFF_PA4)[idx] = make_float4(x,y,z, x*x+y*y+z*z);
  const float gx = xgt[idx*3], gy = xgt[idx*3+1], gz = xgt[idx*3+2];
  reinterpret_cast<float4*>(ws+OFF_PB4)[idx] = make_float4(gx,gy,gz, gx*gx+gy*gy+gz*gz);

  const float al = ap[idx];
  const float asoft = 10.0f * tanhf(al*0.1f);
  const float a = 1.0f/(1.0f + fexp2(-asoft*LOG2E));
  ws[OFF_A  +idx] = a;
  ws[OFF_LA2+idx] = flog2(fmaxf(a,1e-30f));

  const float w = 1.0f/(1.0f + fexp2(-al*LOG2E));
  const float tx = mxp[idx*3]-x,  ty = mxp[idx*3+1]-y,  tz = mxp[idx*3+2]-z;
  const float dx = vp[idx*3]-tx,  dy = vp[idx*3+1]-ty,  dz = vp[idx*3+2]-tz;
  const float se = dx*dx+dy*dy+dz*dz;

  const float sa = wave_sum(a), sw = wave_sum(w), sew = wave_sum(se*w);
  if((threadIdx.x & 63) == 0){
    atomicAdd(&ws[OFF_SUMA+b], sa);
    atomicAdd(&ws[OFF_SCAL+0], sw);
    atomicAdd(&ws[OFF_SCAL+1], sew);
  }
}

// ---------- per-batch max of clamped cost ----------
__global__ __launch_bounds__(256) void k_cmax(float* __restrict__ ws){
  __shared__ float4 sB[2048];
  const int rowbase = blockIdx.x*16;          // 16 rows/block, 4 rows/wave
  const int b = rowbase >> 11;
  const float4* pA = reinterpret_cast<const float4*>(ws+OFF_PA4);
  const float4* pB = reinterpret_cast<const float4*>(ws+OFF_PB4) + b*2048;
  for(int i=threadIdx.x;i<2048;i+=256) sB[i] = pB[i];
  __syncthreads();
  const int lane = threadIdx.x & 63;
  const int r0 = rowbase + ((threadIdx.x>>6)<<2);
  const float4 A0=pA[r0], A1=pA[r0+1], A2=pA[r0+2], A3=pA[r0+3];
  float c0=0,c1=0,c2=0,c3=0;                  // init 0 == clamp at 0
  for(int k=lane;k<2048;k+=64){
    const float4 pt = sB[k];
    float d;
    d = A0.x*pt.x + A0.y*pt.y + A0.z*pt.z; c0 = fmaxf(c0, A0.w + pt.w - 2.0f*d);
    d = A1.x*pt.x + A1.y*pt.y + A1.z*pt.z; c1 = fmaxf(c1, A1.w + pt.w - 2.0f*d);
    d = A2.x*pt.x + A2.y*pt.y + A2.z*pt.z; c2 = fmaxf(c2, A2.w + pt.w - 2.0f*d);
    d = A3.x*pt.x + A3.y*pt.y + A3.z*pt.z; c3 = fmaxf(c3, A3.w + pt.w - 2.0f*d);
  }
  const float cm = wave_max(fmaxf(fmaxf(c0,c1),fmaxf(c2,c3)));
  if(lane==0)
    atomicMax(reinterpret_cast<unsigned*>(ws)+OFF_CMAX+b, __float_as_uint(cm));
}

// ---------- tiny per-batch scalars ----------
__global__ void k_scalars(float* __restrict__ ws){
  const int t = threadIdx.x;
  if(t < 8){
    const float cmax = __uint_as_float(reinterpret_cast<unsigned*>(ws)[OFF_CMAX+t]);
    ws[OFF_SC +t] = NEG20LOG2E/(cmax + 1e-8f);
    ws[OFF_LB2+t] = flog2(fmaxf(ws[OFF_SUMA+t]/2048.0f, 1e-30f));
  }
}

// ---------- one Sinkhorn half-iteration (logsumexp pass) ----------
// ROW: per (b,m) lse over k, writes lu.  !ROW: per (b,k) lse over m, writes lv.
template<bool ROW>
__global__ __launch_bounds__(256) void k_lse(float* __restrict__ ws, int p){
  __shared__ float4 sB[2048];
  __shared__ float  sL[2048];
  const int rowbase = blockIdx.x*16;
  const int b = rowbase >> 11;
  const float4* pA = reinterpret_cast<const float4*>(ws + (ROW?OFF_PA4:OFF_PB4));
  const float4* pB = reinterpret_cast<const float4*>(ws + (ROW?OFF_PB4:OFF_PA4)) + b*2048;
  const float*  lo = ws + (ROW?OFF_LV:OFF_LU) + b*2048;
  float* out = ws + (ROW?OFF_LU:OFF_LV);
  unsigned* xhi = reinterpret_cast<unsigned*>(ws) + OFF_XHI;
  const float Xhi = (p==0) ? 0.0f : dec_ord(xhi[(p-1)*8 + b]);
  const float sc = ws[OFF_SC + b];
  for(int i=threadIdx.x;i<2048;i+=256){ sB[i] = pB[i]; sL[i] = lo[i] - Xhi; }
  __syncthreads();
  const int lane = threadIdx.x & 63;
  const int r0 = rowbase + ((threadIdx.x>>6)<<2);
  const float4 A0=pA[r0], A1=pA[r0+1], A2=pA[r0+2], A3=pA[r0+3];
  float s0=0,s1=0,s2=0,s3=0;
  for(int k=lane;k<2048;k+=64){
    const float4 pt = sB[k];
    const float lx = sL[k];
    float d,c;
    d = A0.x*pt.x + A0.y*pt.y + A0.z*pt.z; c = A0.w + pt.w - 2.0f*d;
    s0 += fexp2(fmaf(fmaxf(c,0.0f), sc, lx));
    d = A1.x*pt.x + A1.y*pt.y + A1.z*pt.z; c = A1.w + pt.w - 2.0f*d;
    s1 += fexp2(fmaf(fmaxf(c,0.0f), sc, lx));
    d = A2.x*pt.x + A2.y*pt.y + A2.z*pt.z; c = A2.w + pt.w - 2.0f*d;
    s2 += fexp2(fmaf(fmaxf(c,0.0f), sc, lx));
    d = A3.x*pt.x + A3.y*pt.y + A3.z*pt.z; c = A3.w + pt.w - 2.0f*d;
    s3 += fexp2(fmaf(fmaxf(c,0.0f), sc, lx));
  }
  s0 = wave_sum(s0); s1 = wave_sum(s1); s2 = wave_sum(s2); s3 = wave_sum(s3);
  float m0,m1,m2,m3;
  if(ROW){
    m0 = ws[OFF_LA2+r0];   m1 = ws[OFF_LA2+r0+1];
    m2 = ws[OFF_LA2+r0+2]; m3 = ws[OFF_LA2+r0+3];
  } else {
    m0 = m1 = m2 = m3 = ws[OFF_LB2 + b];
  }
  const float o0 = TAU*(m0 - (Xhi + flog2(s0)));
  const float o1 = TAU*(m1 - (Xhi + flog2(s1)));
  const float o2 = TAU*(m2 - (Xhi + flog2(s2)));
  const float o3 = TAU*(m3 - (Xhi + flog2(s3)));
  if(lane==0){
    out[r0]=o0; out[r0+1]=o1; out[r0+2]=o2; out[r0+3]=o3;
    atomicMax(&xhi[p*8+b], enc_ord(fmaxf(fmaxf(o0,o1),fmaxf(o2,o3))));
  }
}

// ---------- final pi pass: surv row-sums, BCE, transport sums ----------
__global__ __launch_bounds__(256) void k_final(const float* __restrict__ ap,
                                               float* __restrict__ ws){
  __shared__ float4 sB[2048];
  __shared__ float  sL[2048];
  const int rowbase = blockIdx.x*16;
  const int b = rowbase >> 11;
  const float4* pA = reinterpret_cast<const float4*>(ws+OFF_PA4);
  const float4* pB = reinterpret_cast<const float4*>(ws+OFF_PB4) + b*2048;
  const float* lv = ws + OFF_LV + b*2048;
  const float sc = ws[OFF_SC + b];
  for(int i=threadIdx.x;i<2048;i+=256){ sB[i] = pB[i]; sL[i] = lv[i]; }
  __syncthreads();
  const int lane = threadIdx.x & 63;
  const int r0 = rowbase + ((threadIdx.x>>6)<<2);
  const float4 A0=pA[r0], A1=pA[r0+1], A2=pA[r0+2], A3=pA[r0+3];
  const float lu0=ws[OFF_LU+r0],   lu1=ws[OFF_LU+r0+1];
  const float lu2=ws[OFF_LU+r0+2], lu3=ws[OFF_LU+r0+3];
  float sp0=0,sp1=0,sp2=0,sp3=0,spc=0;
  for(int k=lane;k<2048;k+=64){
    const float4 pt = sB[k];
    const float lvk = sL[k];
    float d,c,kl,pv;
    d = A0.x*pt.x + A0.y*pt.y + A0.z*pt.z; c = A0.w + pt.w - 2.0f*d;
    kl = fmaxf(c,0.0f)*sc; pv = fexp2(kl+lu0+lvk); sp0 += pv; spc = fmaf(pv,kl,spc);
    d = A1.x*pt.x + A1.y*pt.y + A1.z*pt.z; c = A1.w + pt.w - 2.0f*d;
    kl = fmaxf(c,0.0f)*sc; pv = fexp2(kl+lu1+lvk); sp1 += pv; spc = fmaf(pv,kl,spc);
    d = A2.x*pt.x + A2.y*pt.y + A2.z*pt.z; c = A2.w + pt.w - 2.0f*d;
    kl = fmaxf(c,0.0f)*sc; pv = fexp2(kl+lu2+lvk); sp2 += pv; spc = fmaf(pv,kl,spc);
    d = A3.x*pt.x + A3.y*pt.y + A3.z*pt.z; c = A3.w + pt.w - 2.0f*d;
    kl = fmaxf(c,0.0f)*sc; pv = fexp2(kl+lu3+lvk); sp3 += pv; spc = fmaf(pv,kl,spc);
  }
  sp0 = wave_sum(sp0); sp1 = wave_sum(sp1);
  sp2 = wave_sum(sp2); sp3 = wave_sum(sp3);
  spc = wave_sum(spc);
  // epilogue computed uniformly on all lanes (avoids shfl in divergent branch)
  const float sps[4] = {sp0,sp1,sp2,sp3};
  float bce = 0.0f;
  #pragma unroll
  for(int r=0;r<4;r++){
    const int row = r0 + r;
    float yv = sps[r] / (ws[OFF_A+row] + 1e-8f);
    yv = fminf(fmaxf(yv,0.0f),1.0f);
    const float al = ap[row];
    bce += fmaxf(al,0.0f) - al*yv + log1pf(expf(-fabsf(al)));
  }
  if(lane==0){
    atomicAdd(&ws[OFF_SCAL+2], bce);
    atomicAdd(&ws[OFF_SCAL+3], sp0+sp1+sp2+sp3);
    atomicAdd(&ws[OFF_SCAL+4], spc);
  }
}

// ---------- combine ----------
__global__ void k_out(const float* __restrict__ ws, float* __restrict__ out){
  const float sw  = ws[OFF_SCAL+0], sew = ws[OFF_SCAL+1];
  const float bce = ws[OFF_SCAL+2], sp  = ws[OFF_SCAL+3], spc = ws[OFF_SCAL+4];
  const float loss_vel  = sew / fmaxf(sw, 1.0f);
  const float loss_surv = bce / 16384.0f;
  // sum(pi*cost) = spc * (-ln2/20)   since kl' = -20*log2e*cost_n
  const float loss_tr = (spc * (-0.03465735902799726f)) / fmaxf(sp, 1e-8f);
  out[0] = loss_vel + loss_surv + 0.1f*loss_tr;
}

extern "C" void kernel_launch(void* const* d_in, const int* in_sizes, int n_in,
                              void* d_out, int out_size, void* d_ws, size_t ws_size,
                              hipStream_t stream) {
  (void)in_sizes; (void)n_in; (void)out_size; (void)ws_size;
  const float* x0  = (const float*)d_in[0];
  const float* xgt = (const float*)d_in[1];
  const float* vp  = (const float*)d_in[2];
  const float* ap  = (const float*)d_in[3];
  const float* mxp = (const float*)d_in[5];   // t (d_in[4]) unused
  float* ws  = (float*)d_ws;
  float* out = (float*)d_out;

  // zero lv + all accumulators (harness does not re-poison between replays)
  hipMemsetAsync(ws + OFF_LV, 0, (size_t)(OFF_END - OFF_LV)*4, stream);

  k_prep<<<64, 256, 0, stream>>>(x0, xgt, vp, ap, mxp, ws);
  k_cmax<<<1024, 256, 0, stream>>>(ws);
  k_scalars<<<1, 64, 0, stream>>>(ws);
  for(int p=0;p<10;p++){
    if((p&1)==0) k_lse<true ><<<1024, 256, 0, stream>>>(ws, p);
    else         k_lse<false><<<1024, 256, 0, stream>>>(ws, p);
  }
  k_final<<<1024, 256, 0, stream>>>(ap, ws);
  k_out<<<1, 1, 0, stream>>>(ws, out);
}

// Round 3
// 217.464 us; speedup vs baseline: 3.5926x; 3.5926x over previous
//
#include <hip/hip_runtime.h>
#include <hip/hip_bf16.h>
#include <math.h>

// FlowMatchingLoss: B=8, M=K=2048. All log-domain values pre-scaled by log2e
// so hardware exp2/log2 apply directly.
//   K_log' = sc_b * max(c,0),  sc_b = -20*log2e/(cmax_b+1e-8)
// Round-3 change: fix k_out launch (256 threads — round 2 launched it with 1
// thread, so the partial reduction read garbage). Structure otherwise same as
// round 2: block-level LDS pre-reduction + padded atomic slots + partial-store
// reduction to kill same-address atomic serialization.

#define LOG2E 1.4426950408889634f
#define TAU   0.95238095238095238f     // 1.0/(1.0+0.05)
#define NEG20LOG2E (-28.853900817779268f)

// workspace layout, in 4-byte units
enum : int {
  OFF_PA4  = 0,        // B*M float4: x0.xyz, |x0|^2
  OFF_PB4  = 65536,    // B*K float4: xgt.xyz, |xgt|^2
  OFF_A    = 131072,   // a = sigmoid(10*tanh(alpha/10))
  OFF_LA2  = 147456,   // log2(max(a,1e-30))
  OFF_LU   = 163840,   // log_u * log2e
  OFF_LV   = 180224,   // log_v * log2e  (zeroed region starts here)
  OFF_XHI  = 196608,   // 80 slots (10 pass x 8 batch), stride 32 (128B pad)
  OFF_CMAX = 199168,   // 8 slots, stride 32
  OFF_SUMA = 199424,   // 8 slots, stride 32
  OFF_SW   = 199680,   // padded scalar: sum_w
  OFF_SEW  = 199712,   // padded scalar: sum_w*err
  OFF_ZEND = 199744,   // end of zeroed region
  OFF_SC   = 199744,   // 8: K_log' scale per batch
  OFF_LB2  = 199752,   // 8: log2(b) per batch
  OFF_PART = 199760,   // 3*1024 k_final partials (bce, sum_pi, sum_pi*kl')
  OFF_END  = 202832
};

__device__ __forceinline__ float fexp2(float x){ return __builtin_amdgcn_exp2f(x); }
__device__ __forceinline__ float flog2(float x){ return __builtin_amdgcn_logf(x); }

// monotonic float<->uint encoding for atomicMax over signed floats; init 0 < all
__device__ __forceinline__ unsigned enc_ord(float f){
  unsigned u = __float_as_uint(f);
  return (u & 0x80000000u) ? ~u : (u | 0x80000000u);
}
__device__ __forceinline__ float dec_ord(unsigned u){
  unsigned b = (u & 0x80000000u) ? (u ^ 0x80000000u) : ~u;
  return __uint_as_float(b);
}

__device__ __forceinline__ float wave_sum(float v){
  #pragma unroll
  for(int m=32;m;m>>=1) v += __shfl_xor(v,m,64);
  return v;
}
__device__ __forceinline__ float wave_max(float v){
  #pragma unroll
  for(int m=32;m;m>>=1) v = fmaxf(v,__shfl_xor(v,m,64));
  return v;
}

// ---------- prep: pack points+norms, a/log_a, velocity-loss sums ----------
__global__ __launch_bounds__(256) void k_prep(const float* __restrict__ x0,
                                              const float* __restrict__ xgt,
                                              const float* __restrict__ vp,
                                              const float* __restrict__ ap,
                                              const float* __restrict__ mxp,
                                              float* __restrict__ ws){
  __shared__ float rA, rW, rE;
  if(threadIdx.x == 0){ rA = 0.0f; rW = 0.0f; rE = 0.0f; }
  __syncthreads();
  const int idx = blockIdx.x*256 + threadIdx.x;   // block lies in one batch
  const int b = idx >> 11;
  const float x = x0[idx*3], y = x0[idx*3+1], z = x0[idx*3+2];
  reinterpret_cast<float4*>(ws+OFF_PA4)[idx] = make_float4(x,y,z, x*x+y*y+z*z);
  const float gx = xgt[idx*3], gy = xgt[idx*3+1], gz = xgt[idx*3+2];
  reinterpret_cast<float4*>(ws+OFF_PB4)[idx] = make_float4(gx,gy,gz, gx*gx+gy*gy+gz*gz);

  const float al = ap[idx];
  const float asoft = 10.0f * tanhf(al*0.1f);
  const float a = 1.0f/(1.0f + fexp2(-asoft*LOG2E));
  ws[OFF_A  +idx] = a;
  ws[OFF_LA2+idx] = flog2(fmaxf(a,1e-30f));

  const float w = 1.0f/(1.0f + fexp2(-al*LOG2E));
  const float tx = mxp[idx*3]-x,  ty = mxp[idx*3+1]-y,  tz = mxp[idx*3+2]-z;
  const float dx = vp[idx*3]-tx,  dy = vp[idx*3+1]-ty,  dz = vp[idx*3+2]-tz;
  const float se = dx*dx+dy*dy+dz*dz;

  const float sa = wave_sum(a), sw = wave_sum(w), sew = wave_sum(se*w);
  if((threadIdx.x & 63) == 0){
    atomicAdd(&rA, sa); atomicAdd(&rW, sw); atomicAdd(&rE, sew);
  }
  __syncthreads();
  if(threadIdx.x == 0){
    atomicAdd(&ws[OFF_SUMA + b*32], rA);
    atomicAdd(&ws[OFF_SW], rW);
    atomicAdd(&ws[OFF_SEW], rE);
  }
}

// ---------- per-batch max of clamped cost ----------
__global__ __launch_bounds__(256) void k_cmax(float* __restrict__ ws){
  __shared__ float4 sB[2048];
  __shared__ unsigned bmax;
  if(threadIdx.x == 0) bmax = 0u;
  const int rowbase = blockIdx.x*16;          // 16 rows/block, 4 rows/wave
  const int b = rowbase >> 11;
  const float4* pA = reinterpret_cast<const float4*>(ws+OFF_PA4);
  const float4* pB = reinterpret_cast<const float4*>(ws+OFF_PB4) + b*2048;
  for(int i=threadIdx.x;i<2048;i+=256) sB[i] = pB[i];
  __syncthreads();
  const int lane = threadIdx.x & 63;
  const int r0 = rowbase + ((threadIdx.x>>6)<<2);
  const float4 A0=pA[r0], A1=pA[r0+1], A2=pA[r0+2], A3=pA[r0+3];
  float c0=0,c1=0,c2=0,c3=0;                  // init 0 == clamp at 0
  for(int k=lane;k<2048;k+=64){
    const float4 pt = sB[k];
    float d;
    d = A0.x*pt.x + A0.y*pt.y + A0.z*pt.z; c0 = fmaxf(c0, A0.w + pt.w - 2.0f*d);
    d = A1.x*pt.x + A1.y*pt.y + A1.z*pt.z; c1 = fmaxf(c1, A1.w + pt.w - 2.0f*d);
    d = A2.x*pt.x + A2.y*pt.y + A2.z*pt.z; c2 = fmaxf(c2, A2.w + pt.w - 2.0f*d);
    d = A3.x*pt.x + A3.y*pt.y + A3.z*pt.z; c3 = fmaxf(c3, A3.w + pt.w - 2.0f*d);
  }
  const float cm = wave_max(fmaxf(fmaxf(c0,c1),fmaxf(c2,c3)));
  if(lane==0) atomicMax(&bmax, __float_as_uint(cm));   // LDS atomic (nonneg)
  __syncthreads();
  if(threadIdx.x == 0)
    atomicMax(reinterpret_cast<unsigned*>(ws)+OFF_CMAX+b*32, bmax);
}

// ---------- tiny per-batch scalars ----------
__global__ void k_scalars(float* __restrict__ ws){
  const int t = threadIdx.x;
  if(t < 8){
    const float cmax = __uint_as_float(reinterpret_cast<unsigned*>(ws)[OFF_CMAX+t*32]);
    ws[OFF_SC +t] = NEG20LOG2E/(cmax + 1e-8f);
    ws[OFF_LB2+t] = flog2(fmaxf(ws[OFF_SUMA+t*32]/2048.0f, 1e-30f));
  }
}

// ---------- one Sinkhorn half-iteration (logsumexp pass) ----------
// ROW: per (b,m) lse over k, writes lu.  !ROW: per (b,k) lse over m, writes lv.
template<bool ROW>
__global__ __launch_bounds__(256) void k_lse(float* __restrict__ ws, int p){
  __shared__ float4 sB[2048];
  __shared__ float  sL[2048];
  __shared__ unsigned bmax;
  if(threadIdx.x == 0) bmax = 0u;
  const int rowbase = blockIdx.x*16;
  const int b = rowbase >> 11;
  const float4* pA = reinterpret_cast<const float4*>(ws + (ROW?OFF_PA4:OFF_PB4));
  const float4* pB = reinterpret_cast<const float4*>(ws + (ROW?OFF_PB4:OFF_PA4)) + b*2048;
  const float*  lo = ws + (ROW?OFF_LV:OFF_LU) + b*2048;
  float* out = ws + (ROW?OFF_LU:OFF_LV);
  unsigned* xhi = reinterpret_cast<unsigned*>(ws) + OFF_XHI;
  const float Xhi = (p==0) ? 0.0f : dec_ord(xhi[((p-1)*8 + b)*32]);
  const float sc = ws[OFF_SC + b];
  for(int i=threadIdx.x;i<2048;i+=256){ sB[i] = pB[i]; sL[i] = lo[i] - Xhi; }
  __syncthreads();
  const int lane = threadIdx.x & 63;
  const int r0 = rowbase + ((threadIdx.x>>6)<<2);
  const float4 A0=pA[r0], A1=pA[r0+1], A2=pA[r0+2], A3=pA[r0+3];
  float s0=0,s1=0,s2=0,s3=0;
  for(int k=lane;k<2048;k+=64){
    const float4 pt = sB[k];
    const float lx = sL[k];
    float d,c;
    d = A0.x*pt.x + A0.y*pt.y + A0.z*pt.z; c = A0.w + pt.w - 2.0f*d;
    s0 += fexp2(fmaf(fmaxf(c,0.0f), sc, lx));
    d = A1.x*pt.x + A1.y*pt.y + A1.z*pt.z; c = A1.w + pt.w - 2.0f*d;
    s1 += fexp2(fmaf(fmaxf(c,0.0f), sc, lx));
    d = A2.x*pt.x + A2.y*pt.y + A2.z*pt.z; c = A2.w + pt.w - 2.0f*d;
    s2 += fexp2(fmaf(fmaxf(c,0.0f), sc, lx));
    d = A3.x*pt.x + A3.y*pt.y + A3.z*pt.z; c = A3.w + pt.w - 2.0f*d;
    s3 += fexp2(fmaf(fmaxf(c,0.0f), sc, lx));
  }
  s0 = wave_sum(s0); s1 = wave_sum(s1); s2 = wave_sum(s2); s3 = wave_sum(s3);
  float m0,m1,m2,m3;
  if(ROW){
    m0 = ws[OFF_LA2+r0];   m1 = ws[OFF_LA2+r0+1];
    m2 = ws[OFF_LA2+r0+2]; m3 = ws[OFF_LA2+r0+3];
  } else {
    m0 = m1 = m2 = m3 = ws[OFF_LB2 + b];
  }
  const float o0 = TAU*(m0 - (Xhi + flog2(s0)));
  const float o1 = TAU*(m1 - (Xhi + flog2(s1)));
  const float o2 = TAU*(m2 - (Xhi + flog2(s2)));
  const float o3 = TAU*(m3 - (Xhi + flog2(s3)));
  if(lane==0){
    out[r0]=o0; out[r0+1]=o1; out[r0+2]=o2; out[r0+3]=o3;
    atomicMax(&bmax, enc_ord(fmaxf(fmaxf(o0,o1),fmaxf(o2,o3))));  // LDS
  }
  __syncthreads();
  if(threadIdx.x == 0) atomicMax(&xhi[(p*8+b)*32], bmax);
}

// ---------- final pi pass: surv row-sums, BCE, transport sums ----------
__global__ __launch_bounds__(256) void k_final(const float* __restrict__ ap,
                                               float* __restrict__ ws){
  __shared__ float4 sB[2048];
  __shared__ float  sL[2048];
  __shared__ float rB, rS, rC;
  if(threadIdx.x == 0){ rB = 0.0f; rS = 0.0f; rC = 0.0f; }
  const int rowbase = blockIdx.x*16;
  const int b = rowbase >> 11;
  const float4* pA = reinterpret_cast<const float4*>(ws+OFF_PA4);
  const float4* pB = reinterpret_cast<const float4*>(ws+OFF_PB4) + b*2048;
  const float* lv = ws + OFF_LV + b*2048;
  const float sc = ws[OFF_SC + b];
  for(int i=threadIdx.x;i<2048;i+=256){ sB[i] = pB[i]; sL[i] = lv[i]; }
  __syncthreads();
  const int lane = threadIdx.x & 63;
  const int r0 = rowbase + ((threadIdx.x>>6)<<2);
  const float4 A0=pA[r0], A1=pA[r0+1], A2=pA[r0+2], A3=pA[r0+3];
  const float lu0=ws[OFF_LU+r0],   lu1=ws[OFF_LU+r0+1];
  const float lu2=ws[OFF_LU+r0+2], lu3=ws[OFF_LU+r0+3];
  float sp0=0,sp1=0,sp2=0,sp3=0,spc=0;
  for(int k=lane;k<2048;k+=64){
    const float4 pt = sB[k];
    const float lvk = sL[k];
    float d,c,kl,pv;
    d = A0.x*pt.x + A0.y*pt.y + A0.z*pt.z; c = A0.w + pt.w - 2.0f*d;
    kl = fmaxf(c,0.0f)*sc; pv = fexp2(kl+lu0+lvk); sp0 += pv; spc = fmaf(pv,kl,spc);
    d = A1.x*pt.x + A1.y*pt.y + A1.z*pt.z; c = A1.w + pt.w - 2.0f*d;
    kl = fmaxf(c,0.0f)*sc; pv = fexp2(kl+lu1+lvk); sp1 += pv; spc = fmaf(pv,kl,spc);
    d = A2.x*pt.x + A2.y*pt.y + A2.z*pt.z; c = A2.w + pt.w - 2.0f*d;
    kl = fmaxf(c,0.0f)*sc; pv = fexp2(kl+lu2+lvk); sp2 += pv; spc = fmaf(pv,kl,spc);
    d = A3.x*pt.x + A3.y*pt.y + A3.z*pt.z; c = A3.w + pt.w - 2.0f*d;
    kl = fmaxf(c,0.0f)*sc; pv = fexp2(kl+lu3+lvk); sp3 += pv; spc = fmaf(pv,kl,spc);
  }
  sp0 = wave_sum(sp0); sp1 = wave_sum(sp1);
  sp2 = wave_sum(sp2); sp3 = wave_sum(sp3);
  spc = wave_sum(spc);
  // epilogue computed uniformly on all lanes
  const float sps[4] = {sp0,sp1,sp2,sp3};
  float bce = 0.0f;
  #pragma unroll
  for(int r=0;r<4;r++){
    const int row = r0 + r;
    float yv = sps[r] / (ws[OFF_A+row] + 1e-8f);
    yv = fminf(fmaxf(yv,0.0f),1.0f);
    const float al = ap[row];
    // log1p(exp(-|x|)) = ln2 * log2(1 + 2^(-|x|*log2e))
    bce += fmaxf(al,0.0f) - al*yv
         + 0.69314718056f*flog2(1.0f + fexp2(-fabsf(al)*LOG2E));
  }
  if(lane==0){
    atomicAdd(&rB, bce);                 // LDS atomics across the 4 waves
    atomicAdd(&rS, sp0+sp1+sp2+sp3);
    atomicAdd(&rC, spc);
  }
  __syncthreads();
  if(threadIdx.x == 0){                  // plain stores, no global atomics
    ws[OFF_PART +        blockIdx.x] = rB;
    ws[OFF_PART + 1024 + blockIdx.x] = rS;
    ws[OFF_PART + 2048 + blockIdx.x] = rC;
  }
}

// ---------- combine ----------
__global__ __launch_bounds__(256) void k_out(const float* __restrict__ ws,
                                             float* __restrict__ out){
  __shared__ float sb[3][4];
  float pb=0, ps=0, pc=0;
  for(int i=threadIdx.x;i<1024;i+=256){
    pb += ws[OFF_PART+i];
    ps += ws[OFF_PART+1024+i];
    pc += ws[OFF_PART+2048+i];
  }
  pb = wave_sum(pb); ps = wave_sum(ps); pc = wave_sum(pc);
  const int w = threadIdx.x>>6;
  if((threadIdx.x&63)==0){ sb[0][w]=pb; sb[1][w]=ps; sb[2][w]=pc; }
  __syncthreads();
  if(threadIdx.x==0){
    const float bce = sb[0][0]+sb[0][1]+sb[0][2]+sb[0][3];
    const float sp  = sb[1][0]+sb[1][1]+sb[1][2]+sb[1][3];
    const float spc = sb[2][0]+sb[2][1]+sb[2][2]+sb[2][3];
    const float sw  = ws[OFF_SW], sew = ws[OFF_SEW];
    const float loss_vel  = sew / fmaxf(sw, 1.0f);
    const float loss_surv = bce / 16384.0f;
    // sum(pi*cost_n) = spc * (-ln2/20)  since kl' = -20*log2e*cost_n
    const float loss_tr = (spc * (-0.03465735902799726f)) / fmaxf(sp, 1e-8f);
    out[0] = loss_vel + loss_surv + 0.1f*loss_tr;
  }
}

extern "C" void kernel_launch(void* const* d_in, const int* in_sizes, int n_in,
                              void* d_out, int out_size, void* d_ws, size_t ws_size,
                              hipStream_t stream) {
  (void)in_sizes; (void)n_in; (void)out_size; (void)ws_size;
  const float* x0  = (const float*)d_in[0];
  const float* xgt = (const float*)d_in[1];
  const float* vp  = (const float*)d_in[2];
  const float* ap  = (const float*)d_in[3];
  const float* mxp = (const float*)d_in[5];   // t (d_in[4]) unused
  float* ws  = (float*)d_ws;
  float* out = (float*)d_out;

  // zero lv + all atomic accumulators (harness does not re-poison per replay)
  hipMemsetAsync(ws + OFF_LV, 0, (size_t)(OFF_ZEND - OFF_LV)*4, stream);

  k_prep<<<64, 256, 0, stream>>>(x0, xgt, vp, ap, mxp, ws);
  k_cmax<<<1024, 256, 0, stream>>>(ws);
  k_scalars<<<1, 64, 0, stream>>>(ws);
  for(int p=0;p<10;p++){
    if((p&1)==0) k_lse<true ><<<1024, 256, 0, stream>>>(ws, p);
    else         k_lse<false><<<1024, 256, 0, stream>>>(ws, p);
  }
  k_final<<<1024, 256, 0, stream>>>(ap, ws);
  k_out<<<1, 256, 0, stream>>>(ws, out);   // FIX: was <<<1,1>>> in round 2
}

// Round 4
// 194.400 us; speedup vs baseline: 4.0188x; 1.1186x over previous
//
#include <hip/hip_runtime.h>
#include <hip/hip_bf16.h>
#include <math.h>

// FlowMatchingLoss: B=8, M=K=2048. Log-domain values pre-scaled by log2e so
// hardware exp2/log2 apply directly.
//   K_log' = sc_b * max(c,0),  sc_b = -20*log2e/(cmax_b+1e-8)
// Round-4: no memset, no global atomics, no zero-init. All cross-block
// reductions are plain per-block partial stores, reduced in the NEXT kernel's
// wave-0 prologue (overlapped with LDS staging). 8 rows/wave (512-block heavy
// passes) halves staging redundancy and doubles work per ds_read_b128.

#define LOG2E 1.4426950408889634f
#define TAU   0.95238095238095238f     // 1.0/(1.0+0.05)
#define NEG20LOG2E (-28.853900817779268f)

// workspace layout, in 4-byte units
enum : int {
  OFF_PA4   = 0,        // B*M float4: x0.xyz, |x0|^2
  OFF_PB4   = 65536,    // B*K float4: xgt.xyz, |xgt|^2
  OFF_A     = 131072,   // a = sigmoid(10*tanh(alpha/10))
  OFF_LA2   = 147456,   // log2(max(a,1e-30))
  OFF_LU    = 163840,   // log_u * log2e
  OFF_LV    = 180224,   // log_v * log2e
  OFF_XPART = 196608,   // 10 passes x 512 per-block output-max partials
  OFF_CPART = 201728,   // 512 per-block cmax partials
  OFF_SUMAP = 202240,   // 64 per-block sum(a) partials (8 per batch)
  OFF_SWP   = 202304,   // 64 per-block sum(w) partials
  OFF_SEWP  = 202368,   // 64 per-block sum(w*err) partials
  OFF_FPART = 202432,   // 3*512 k_final partials (bce, sum_pi, sum_pi*kl')
  OFF_END   = 203968
};

__device__ __forceinline__ float fexp2(float x){ return __builtin_amdgcn_exp2f(x); }
__device__ __forceinline__ float flog2(float x){ return __builtin_amdgcn_logf(x); }

__device__ __forceinline__ float wave_sum(float v){
  #pragma unroll
  for(int m=32;m;m>>=1) v += __shfl_xor(v,m,64);
  return v;
}
__device__ __forceinline__ float wave_max(float v){
  #pragma unroll
  for(int m=32;m;m>>=1) v = fmaxf(v,__shfl_xor(v,m,64));
  return v;
}

// ---------- prep: pack points+norms, a/log_a, velocity partials ----------
__global__ __launch_bounds__(256) void k_prep(const float* __restrict__ x0,
                                              const float* __restrict__ xgt,
                                              const float* __restrict__ vp,
                                              const float* __restrict__ ap,
                                              const float* __restrict__ mxp,
                                              float* __restrict__ ws){
  __shared__ float rA, rW, rE;
  if(threadIdx.x == 0){ rA = 0.0f; rW = 0.0f; rE = 0.0f; }
  __syncthreads();
  const int idx = blockIdx.x*256 + threadIdx.x;   // block lies in one batch
  const float x = x0[idx*3], y = x0[idx*3+1], z = x0[idx*3+2];
  reinterpret_cast<float4*>(ws+OFF_PA4)[idx] = make_float4(x,y,z, x*x+y*y+z*z);
  const float gx = xgt[idx*3], gy = xgt[idx*3+1], gz = xgt[idx*3+2];
  reinterpret_cast<float4*>(ws+OFF_PB4)[idx] = make_float4(gx,gy,gz, gx*gx+gy*gy+gz*gz);

  const float al = ap[idx];
  const float asoft = 10.0f * tanhf(al*0.1f);
  const float a = 1.0f/(1.0f + fexp2(-asoft*LOG2E));
  ws[OFF_A  +idx] = a;
  ws[OFF_LA2+idx] = flog2(fmaxf(a,1e-30f));

  const float w = 1.0f/(1.0f + fexp2(-al*LOG2E));
  const float tx = mxp[idx*3]-x,  ty = mxp[idx*3+1]-y,  tz = mxp[idx*3+2]-z;
  const float dx = vp[idx*3]-tx,  dy = vp[idx*3+1]-ty,  dz = vp[idx*3+2]-tz;
  const float se = dx*dx+dy*dy+dz*dz;

  const float sa = wave_sum(a), sw = wave_sum(w), sew = wave_sum(se*w);
  if((threadIdx.x & 63) == 0){
    atomicAdd(&rA, sa); atomicAdd(&rW, sw); atomicAdd(&rE, sew);  // LDS only
  }
  __syncthreads();
  if(threadIdx.x == 0){                       // plain stores, no global atomics
    ws[OFF_SUMAP + blockIdx.x] = rA;
    ws[OFF_SWP   + blockIdx.x] = rW;
    ws[OFF_SEWP  + blockIdx.x] = rE;
  }
}

// ---------- per-batch max of clamped cost (per-block partial) ----------
__global__ __launch_bounds__(256) void k_cmax(float* __restrict__ ws){
  __shared__ float4 sB[2048];
  __shared__ float sbm[4];
  const int blk = blockIdx.x;
  const int rowbase = blk*32;                 // 32 rows/block, 8 rows/wave
  const int b = rowbase >> 11;
  const int tid = threadIdx.x, lane = tid & 63;
  const float4* pA = reinterpret_cast<const float4*>(ws+OFF_PA4);
  const float4* pB = reinterpret_cast<const float4*>(ws+OFF_PB4) + b*2048;
  for(int i=tid;i<2048;i+=256) sB[i] = pB[i];
  __syncthreads();
  const int r0 = rowbase + ((tid>>6)<<3);
  float4 A[8]; float c[8];
  #pragma unroll
  for(int r=0;r<8;r++){ A[r] = pA[r0+r]; c[r] = 0.0f; }  // init 0 == clamp
  for(int k=lane;k<2048;k+=64){
    const float4 pt = sB[k];
    #pragma unroll
    for(int r=0;r<8;r++){
      const float d = A[r].x*pt.x + A[r].y*pt.y + A[r].z*pt.z;
      c[r] = fmaxf(c[r], A[r].w + pt.w - 2.0f*d);
    }
  }
  float cm = c[0];
  #pragma unroll
  for(int r=1;r<8;r++) cm = fmaxf(cm, c[r]);
  cm = wave_max(cm);
  if(lane==0) sbm[tid>>6] = cm;
  __syncthreads();
  if(tid==0)
    ws[OFF_CPART+blk] = fmaxf(fmaxf(sbm[0],sbm[1]),fmaxf(sbm[2],sbm[3]));
}

// ---------- one Sinkhorn half-iteration (logsumexp pass) ----------
// ROW: per (b,m) lse over k, writes lu.  !ROW: per (b,k) lse over m, writes lv.
// FIRST: p==0, incoming log_v is identically 0 (skip sL entirely).
template<bool ROW, bool FIRST>
__global__ __launch_bounds__(256) void k_lse(float* __restrict__ ws, int p){
  __shared__ float4 sB[2048];
  __shared__ float  sL[2048];
  __shared__ float sbm[4];
  __shared__ float sSC, sXHI, sLB2;
  const int blk = blockIdx.x;
  const int rowbase = blk*32;
  const int b = rowbase >> 11;
  const int tid = threadIdx.x, lane = tid & 63;

  // wave-0 prologue: reduce per-batch scalars from previous kernels' partials
  if(tid < 64){
    float cm = wave_max(ws[OFF_CPART + b*64 + lane]);
    float xh = 0.0f;
    if(!FIRST) xh = wave_max(ws[OFF_XPART + (p-1)*512 + b*64 + lane]);
    float sa = (lane < 8) ? ws[OFF_SUMAP + b*8 + lane] : 0.0f;
    sa = wave_sum(sa);
    if(lane == 0){
      sSC  = NEG20LOG2E/(cm + 1e-8f);
      sXHI = xh;
      sLB2 = flog2(fmaxf(sa*(1.0f/2048.0f), 1e-30f));
    }
  }
  const float4* pA = reinterpret_cast<const float4*>(ws + (ROW?OFF_PA4:OFF_PB4));
  const float4* pB = reinterpret_cast<const float4*>(ws + (ROW?OFF_PB4:OFF_PA4)) + b*2048;
  const float*  lo = ws + (ROW?OFF_LV:OFF_LU) + b*2048;
  float* out = ws + (ROW?OFF_LU:OFF_LV);
  for(int i=tid;i<2048;i+=256){ sB[i] = pB[i]; if(!FIRST) sL[i] = lo[i]; }
  __syncthreads();
  const float sc  = sSC;
  const float Xhi = FIRST ? 0.0f : sXHI;

  const int r0 = rowbase + ((tid>>6)<<3);
  float4 A[8]; float s[8];
  #pragma unroll
  for(int r=0;r<8;r++){ A[r] = pA[r0+r]; s[r] = 0.0f; }
  for(int k=lane;k<2048;k+=64){
    const float4 pt = sB[k];
    const float lxk = FIRST ? 0.0f : (sL[k] - Xhi);
    #pragma unroll
    for(int r=0;r<8;r++){
      const float d = A[r].x*pt.x + A[r].y*pt.y + A[r].z*pt.z;
      const float c = A[r].w + pt.w - 2.0f*d;
      s[r] += fexp2(fmaf(fmaxf(c,0.0f), sc, lxk));
    }
  }
  #pragma unroll
  for(int r=0;r<8;r++) s[r] = wave_sum(s[r]);
  if(lane==0){
    float om = -1e30f;
    #pragma unroll
    for(int r=0;r<8;r++){
      const int row = r0 + r;
      const float mr = ROW ? ws[OFF_LA2+row] : sLB2;
      const float o  = TAU*(mr - (Xhi + flog2(s[r])));
      out[row] = o;
      om = fmaxf(om, o);
    }
    sbm[tid>>6] = om;
  }
  __syncthreads();
  if(tid==0)
    ws[OFF_XPART + p*512 + blk] =
        fmaxf(fmaxf(sbm[0],sbm[1]),fmaxf(sbm[2],sbm[3]));
}

// ---------- final pi pass: surv row-sums, BCE, transport partials ----------
__global__ __launch_bounds__(256) void k_final(const float* __restrict__ ap,
                                               float* __restrict__ ws){
  __shared__ float4 sB[2048];
  __shared__ float  sL[2048];
  __shared__ float rB, rS, rC, sSC;
  const int blk = blockIdx.x;
  const int rowbase = blk*32;
  const int b = rowbase >> 11;
  const int tid = threadIdx.x, lane = tid & 63;
  if(tid == 0){ rB = 0.0f; rS = 0.0f; rC = 0.0f; }
  if(tid < 64){
    const float cm = wave_max(ws[OFF_CPART + b*64 + lane]);
    if(lane == 0) sSC = NEG20LOG2E/(cm + 1e-8f);
  }
  const float4* pA = reinterpret_cast<const float4*>(ws+OFF_PA4);
  const float4* pB = reinterpret_cast<const float4*>(ws+OFF_PB4) + b*2048;
  const float* lv = ws + OFF_LV + b*2048;
  for(int i=tid;i<2048;i+=256){ sB[i] = pB[i]; sL[i] = lv[i]; }
  __syncthreads();
  const float sc = sSC;
  const int r0 = rowbase + ((tid>>6)<<3);
  float4 A[8]; float sp[8], lu[8];
  #pragma unroll
  for(int r=0;r<8;r++){ A[r]=pA[r0+r]; sp[r]=0.0f; lu[r]=ws[OFF_LU+r0+r]; }
  float spc = 0.0f;
  for(int k=lane;k<2048;k+=64){
    const float4 pt = sB[k];
    const float lvk = sL[k];
    #pragma unroll
    for(int r=0;r<8;r++){
      const float d  = A[r].x*pt.x + A[r].y*pt.y + A[r].z*pt.z;
      const float c  = A[r].w + pt.w - 2.0f*d;
      const float kl = fmaxf(c,0.0f)*sc;
      const float pv = fexp2(kl + lu[r] + lvk);
      sp[r] += pv; spc = fmaf(pv, kl, spc);
    }
  }
  #pragma unroll
  for(int r=0;r<8;r++) sp[r] = wave_sum(sp[r]);
  spc = wave_sum(spc);
  // epilogue computed uniformly on all lanes
  float bce = 0.0f, spt = 0.0f;
  #pragma unroll
  for(int r=0;r<8;r++){
    const int row = r0 + r;
    float yv = sp[r] / (ws[OFF_A+row] + 1e-8f);
    yv = fminf(fmaxf(yv,0.0f),1.0f);
    const float al = ap[row];
    // log1p(exp(-|x|)) = ln2 * log2(1 + 2^(-|x|*log2e))
    bce += fmaxf(al,0.0f) - al*yv
         + 0.69314718056f*flog2(1.0f + fexp2(-fabsf(al)*LOG2E));
    spt += sp[r];
  }
  if(lane==0){
    atomicAdd(&rB, bce);                 // LDS atomics across the 4 waves
    atomicAdd(&rS, spt);
    atomicAdd(&rC, spc);
  }
  __syncthreads();
  if(tid == 0){                          // plain stores
    ws[OFF_FPART +        blk] = rB;
    ws[OFF_FPART + 512  + blk] = rS;
    ws[OFF_FPART + 1024 + blk] = rC;
  }
}

// ---------- combine ----------
__global__ __launch_bounds__(256) void k_out(const float* __restrict__ ws,
                                             float* __restrict__ out){
  __shared__ float sb[5][4];
  const int tid = threadIdx.x;
  float pb=0, ps=0, pc=0, pw=0, pe=0;
  for(int i=tid;i<512;i+=256){
    pb += ws[OFF_FPART+i];
    ps += ws[OFF_FPART+512+i];
    pc += ws[OFF_FPART+1024+i];
  }
  if(tid < 64){ pw = ws[OFF_SWP+tid]; pe = ws[OFF_SEWP+tid]; }
  pb = wave_sum(pb); ps = wave_sum(ps); pc = wave_sum(pc);
  pw = wave_sum(pw); pe = wave_sum(pe);
  const int w = tid>>6;
  if((tid&63)==0){ sb[0][w]=pb; sb[1][w]=ps; sb[2][w]=pc; sb[3][w]=pw; sb[4][w]=pe; }
  __syncthreads();
  if(tid==0){
    const float bce = sb[0][0]+sb[0][1]+sb[0][2]+sb[0][3];
    const float sp  = sb[1][0]+sb[1][1]+sb[1][2]+sb[1][3];
    const float spc = sb[2][0]+sb[2][1]+sb[2][2]+sb[2][3];
    const float sw  = sb[3][0]+sb[3][1]+sb[3][2]+sb[3][3];
    const float sew = sb[4][0]+sb[4][1]+sb[4][2]+sb[4][3];
    const float loss_vel  = sew / fmaxf(sw, 1.0f);
    const float loss_surv = bce / 16384.0f;
    // sum(pi*cost_n) = spc * (-ln2/20)  since kl' = -20*log2e*cost_n
    const float loss_tr = (spc * (-0.03465735902799726f)) / fmaxf(sp, 1e-8f);
    out[0] = loss_vel + loss_surv + 0.1f*loss_tr;
  }
}

extern "C" void kernel_launch(void* const* d_in, const int* in_sizes, int n_in,
                              void* d_out, int out_size, void* d_ws, size_t ws_size,
                              hipStream_t stream) {
  (void)in_sizes; (void)n_in; (void)out_size; (void)ws_size;
  const float* x0  = (const float*)d_in[0];
  const float* xgt = (const float*)d_in[1];
  const float* vp  = (const float*)d_in[2];
  const float* ap  = (const float*)d_in[3];
  const float* mxp = (const float*)d_in[5];   // t (d_in[4]) unused
  float* ws  = (float*)d_ws;
  float* out = (float*)d_out;

  k_prep<<<64, 256, 0, stream>>>(x0, xgt, vp, ap, mxp, ws);
  k_cmax<<<512, 256, 0, stream>>>(ws);
  k_lse<true,true><<<512, 256, 0, stream>>>(ws, 0);
  for(int p=1;p<10;p++){
    if(p&1) k_lse<false,false><<<512, 256, 0, stream>>>(ws, p);
    else    k_lse<true ,false><<<512, 256, 0, stream>>>(ws, p);
  }
  k_final<<<512, 256, 0, stream>>>(ap, ws);
  k_out<<<1, 256, 0, stream>>>(ws, out);
}

// Round 5
// 133.129 us; speedup vs baseline: 5.8685x; 1.4602x over previous
//
#include <hip/hip_runtime.h>
#include <hip/hip_bf16.h>
#include <math.h>

// FlowMatchingLoss: B=8, M=K=2048. Log-domain values pre-scaled by log2e so
// hardware exp2/log2 apply directly.
// Round-5: fold the whole exp2 argument into one fma chain:
//   arg = (-2sc*b)·a + [sc|b|^2 + lv - Xhi] + sc|a|^2
// staged as float4(n2sc*bx, n2sc*by, n2sc*bz, sc|b|^2+lv-Xhi) -> inner loop is
// 1 ds_read_b128 + (add,3fma,exp2,add) per row. Clamp max(c,0) dropped in lse
// (c<0 only from fp rounding near zero distance; ~1e-6 relative effect).
// Geometry: 512 blocks x 512 threads, 4 rows/wave -> 4 waves/SIMD.

#define LOG2E 1.4426950408889634f
#define TAU   0.95238095238095238f     // 1/(1+0.05)
#define NEG20LOG2E (-28.853900817779268f)

// workspace layout, in 4-byte units
enum : int {
  OFF_PA4   = 0,        // B*M float4: x0.xyz, |x0|^2
  OFF_PB4   = 65536,    // B*K float4: xgt.xyz, |xgt|^2
  OFF_A     = 131072,   // a = sigmoid(10*tanh(alpha/10))
  OFF_LA2   = 147456,   // log2(max(a,1e-30))
  OFF_LU    = 163840,   // log_u * log2e
  OFF_LV    = 180224,   // log_v * log2e
  OFF_XPART = 196608,   // 10 passes x 512 per-block output-max partials
  OFF_CPART = 201728,   // 512 per-block cmax partials (64 per batch)
  OFF_SUMAP = 202240,   // 256 per-block sum(a) partials (32 per batch)
  OFF_SWP   = 202496,   // 256 per-block sum(w) partials
  OFF_SEWP  = 202752,   // 256 per-block sum(w*err) partials
  OFF_FPART = 203008,   // 3*512 k_final partials (bce, sum_pi, sum_pi*klog)
  OFF_END   = 204544
};

__device__ __forceinline__ float fexp2(float x){ return __builtin_amdgcn_exp2f(x); }
__device__ __forceinline__ float flog2(float x){ return __builtin_amdgcn_logf(x); }

__device__ __forceinline__ float wave_sum(float v){
  #pragma unroll
  for(int m=32;m;m>>=1) v += __shfl_xor(v,m,64);
  return v;
}
__device__ __forceinline__ float wave_max(float v){
  #pragma unroll
  for(int m=32;m;m>>=1) v = fmaxf(v,__shfl_xor(v,m,64));
  return v;
}

// ---------- prep: pack points+norms, a/log_a, velocity partials ----------
// 256 blocks x 64 threads (1 wave), 64 points each; blocks batch-aligned.
__global__ __launch_bounds__(64) void k_prep(const float* __restrict__ x0,
                                             const float* __restrict__ xgt,
                                             const float* __restrict__ vp,
                                             const float* __restrict__ ap,
                                             const float* __restrict__ mxp,
                                             float* __restrict__ ws){
  const int idx = blockIdx.x*64 + threadIdx.x;
  const float x = x0[idx*3], y = x0[idx*3+1], z = x0[idx*3+2];
  reinterpret_cast<float4*>(ws+OFF_PA4)[idx] = make_float4(x,y,z, x*x+y*y+z*z);
  const float gx = xgt[idx*3], gy = xgt[idx*3+1], gz = xgt[idx*3+2];
  reinterpret_cast<float4*>(ws+OFF_PB4)[idx] = make_float4(gx,gy,gz, gx*gx+gy*gy+gz*gz);

  const float al = ap[idx];
  const float asoft = 10.0f * tanhf(al*0.1f);
  const float a = 1.0f/(1.0f + fexp2(-asoft*LOG2E));
  ws[OFF_A  +idx] = a;
  ws[OFF_LA2+idx] = flog2(fmaxf(a,1e-30f));

  const float w = 1.0f/(1.0f + fexp2(-al*LOG2E));
  const float tx = mxp[idx*3]-x,  ty = mxp[idx*3+1]-y,  tz = mxp[idx*3+2]-z;
  const float dx = vp[idx*3]-tx,  dy = vp[idx*3+1]-ty,  dz = vp[idx*3+2]-tz;
  const float se = dx*dx+dy*dy+dz*dz;

  const float sa = wave_sum(a), sw = wave_sum(w), sew = wave_sum(se*w);
  if(threadIdx.x == 0){                       // plain stores, no atomics
    ws[OFF_SUMAP + blockIdx.x] = sa;          // batch = blockIdx.x>>5
    ws[OFF_SWP   + blockIdx.x] = sw;
    ws[OFF_SEWP  + blockIdx.x] = sew;
  }
}

// ---------- per-batch max of clamped cost (per-block partial) ----------
__global__ __launch_bounds__(512,4) void k_cmax(float* __restrict__ ws){
  __shared__ float4 sB[2048];
  __shared__ float sbm[8];
  const int blk = blockIdx.x, tid = threadIdx.x, lane = tid&63, wid = tid>>6;
  const int rowbase = blk*32, b = rowbase>>11;  // 32 rows/block, 4 rows/wave
  const float4* pA = reinterpret_cast<const float4*>(ws+OFF_PA4);
  const float4* pB = reinterpret_cast<const float4*>(ws+OFF_PB4) + b*2048;
  for(int i=tid;i<2048;i+=512) sB[i] = pB[i];
  __syncthreads();
  const int r0 = rowbase + (wid<<2);
  float4 A[4]; float c[4];
  #pragma unroll
  for(int r=0;r<4;r++){ A[r] = pA[r0+r]; c[r] = 0.0f; }  // init 0 == clamp
  #pragma unroll 2
  for(int k=lane;k<2048;k+=64){
    const float4 pt = sB[k];
    #pragma unroll
    for(int r=0;r<4;r++){
      const float d = A[r].x*pt.x + A[r].y*pt.y + A[r].z*pt.z;
      c[r] = fmaxf(c[r], A[r].w + pt.w - 2.0f*d);
    }
  }
  const float cm = wave_max(fmaxf(fmaxf(c[0],c[1]),fmaxf(c[2],c[3])));
  if(lane==0) sbm[wid] = cm;
  __syncthreads();
  if(tid==0){
    float m = sbm[0];
    #pragma unroll
    for(int i=1;i<8;i++) m = fmaxf(m, sbm[i]);
    ws[OFF_CPART+blk] = m;
  }
}

// ---------- one Sinkhorn half-iteration (logsumexp pass) ----------
// ROW: per (b,m) lse over k, writes lu.  !ROW: per (b,k) lse over m, writes lv.
// FIRST: p==0, incoming log_v is identically 0.
template<bool ROW, bool FIRST>
__global__ __launch_bounds__(512,4) void k_lse(float* __restrict__ ws, int p){
  __shared__ float4 sB[2048];
  __shared__ float sbm[8];
  const int blk = blockIdx.x, tid = threadIdx.x, lane = tid&63, wid = tid>>6;
  const int rowbase = blk*32, b = rowbase>>11;

  // per-wave redundant prologue: reduce per-batch scalars from partials
  // (butterfly leaves result in all lanes; no LDS round-trip, no extra sync)
  const float cm = wave_max(ws[OFF_CPART + b*64 + lane]);
  const float sc = NEG20LOG2E/(cm + 1e-8f);
  float Xhi = 0.0f;
  if(!FIRST) Xhi = wave_max(ws[OFF_XPART + (p-1)*512 + b*64 + lane]);
  float lb2 = 0.0f;
  if(!ROW){
    float sa = (lane < 32) ? ws[OFF_SUMAP + b*32 + lane] : 0.0f;
    sa = wave_sum(sa);
    lb2 = flog2(fmaxf(sa*(1.0f/2048.0f), 1e-30f));
  }

  const float4* pA = reinterpret_cast<const float4*>(ws + (ROW?OFF_PA4:OFF_PB4));
  const float4* pP = reinterpret_cast<const float4*>(ws + (ROW?OFF_PB4:OFF_PA4)) + b*2048;
  const float*  lo = ws + (ROW?OFF_LV:OFF_LU) + b*2048;
  float* out = ws + (ROW?OFF_LU:OFF_LV);
  const float n2sc = -2.0f*sc;
  for(int i=tid;i<2048;i+=512){
    const float4 q = pP[i];
    const float lvi = FIRST ? 0.0f : lo[i];
    sB[i] = make_float4(n2sc*q.x, n2sc*q.y, n2sc*q.z,
                        fmaf(sc, q.w, lvi - Xhi));
  }
  __syncthreads();

  const int r0 = rowbase + (wid<<2);
  float4 A[4]; float base[4], s[4];
  #pragma unroll
  for(int r=0;r<4;r++){ A[r] = pA[r0+r]; base[r] = sc*A[r].w; s[r] = 0.0f; }
  #pragma unroll 2
  for(int k=lane;k<2048;k+=64){
    const float4 pt = sB[k];
    #pragma unroll
    for(int r=0;r<4;r++){
      const float arg = fmaf(A[r].x, pt.x, fmaf(A[r].y, pt.y,
                        fmaf(A[r].z, pt.z, base[r] + pt.w)));
      s[r] += fexp2(arg);
    }
  }
  #pragma unroll
  for(int r=0;r<4;r++) s[r] = wave_sum(s[r]);
  if(lane==0){
    float om = -1e30f;
    #pragma unroll
    for(int r=0;r<4;r++){
      const int row = r0 + r;
      const float mr = ROW ? ws[OFF_LA2+row] : lb2;
      const float o  = TAU*(mr - (Xhi + flog2(s[r])));
      out[row] = o;
      om = fmaxf(om, o);
    }
    sbm[wid] = om;
  }
  __syncthreads();
  if(tid==0){
    float m = sbm[0];
    #pragma unroll
    for(int i=1;i<8;i++) m = fmaxf(m, sbm[i]);
    ws[OFF_XPART + p*512 + blk] = m;
  }
}

// ---------- final pi pass: surv row-sums, BCE, transport partials ----------
// klog = arg - lu_r - lv_k, so sum(pi*klog) = sum(pv*arg) - sum_r lu_r*sp_r
//                                             - sum(pv*lv_k)
__global__ __launch_bounds__(512,4) void k_final(const float* __restrict__ ap,
                                                 float* __restrict__ ws){
  __shared__ float4 sB[2048];
  __shared__ float  sL[2048];
  __shared__ float sbb[8], sbs[8], sbc[8];
  const int blk = blockIdx.x, tid = threadIdx.x, lane = tid&63, wid = tid>>6;
  const int rowbase = blk*32, b = rowbase>>11;

  const float cm = wave_max(ws[OFF_CPART + b*64 + lane]);
  const float sc = NEG20LOG2E/(cm + 1e-8f);
  const float n2sc = -2.0f*sc;

  const float4* pA = reinterpret_cast<const float4*>(ws+OFF_PA4);
  const float4* pB = reinterpret_cast<const float4*>(ws+OFF_PB4) + b*2048;
  const float* lv = ws + OFF_LV + b*2048;
  for(int i=tid;i<2048;i+=512){
    const float4 q = pB[i];
    const float lvi = lv[i];
    sB[i] = make_float4(n2sc*q.x, n2sc*q.y, n2sc*q.z, fmaf(sc, q.w, lvi));
    sL[i] = lvi;
  }
  __syncthreads();

  const int r0 = rowbase + (wid<<2);
  float4 A[4]; float base[4], lu[4], sp[4];
  #pragma unroll
  for(int r=0;r<4;r++){
    A[r] = pA[r0+r];
    lu[r] = ws[OFF_LU+r0+r];
    base[r] = fmaf(sc, A[r].w, lu[r]);
    sp[r] = 0.0f;
  }
  float spa = 0.0f, spl = 0.0f;
  #pragma unroll 2
  for(int k=lane;k<2048;k+=64){
    const float4 pt = sB[k];
    const float lvk = sL[k];
    #pragma unroll
    for(int r=0;r<4;r++){
      const float arg = fmaf(A[r].x, pt.x, fmaf(A[r].y, pt.y,
                        fmaf(A[r].z, pt.z, base[r] + pt.w)));
      const float pv = fexp2(arg);
      sp[r] += pv;
      spa = fmaf(pv, arg, spa);
      spl = fmaf(pv, lvk, spl);
    }
  }
  #pragma unroll
  for(int r=0;r<4;r++) sp[r] = wave_sum(sp[r]);
  spa = wave_sum(spa); spl = wave_sum(spl);
  // uniform epilogue on all lanes (butterfly results are lane-uniform)
  float spc = spa - spl, bce = 0.0f, spt = 0.0f;
  #pragma unroll
  for(int r=0;r<4;r++){
    const int row = r0 + r;
    spc -= lu[r]*sp[r];
    float yv = sp[r] / (ws[OFF_A+row] + 1e-8f);
    yv = fminf(fmaxf(yv,0.0f),1.0f);
    const float al = ap[row];
    // log1p(exp(-|x|)) = ln2 * log2(1 + 2^(-|x|*log2e))
    bce += fmaxf(al,0.0f) - al*yv
         + 0.69314718056f*flog2(1.0f + fexp2(-fabsf(al)*LOG2E));
    spt += sp[r];
  }
  if(lane==0){ sbb[wid]=bce; sbs[wid]=spt; sbc[wid]=spc; }
  __syncthreads();
  if(tid==0){
    float tb=0, ts=0, tc=0;
    #pragma unroll
    for(int i=0;i<8;i++){ tb+=sbb[i]; ts+=sbs[i]; tc+=sbc[i]; }
    ws[OFF_FPART +        blk] = tb;
    ws[OFF_FPART + 512  + blk] = ts;
    ws[OFF_FPART + 1024 + blk] = tc;
  }
}

// ---------- combine ----------
__global__ __launch_bounds__(256) void k_out(const float* __restrict__ ws,
                                             float* __restrict__ out){
  __shared__ float sb[5][4];
  const int tid = threadIdx.x;
  float pb=0, ps=0, pc=0;
  for(int i=tid;i<512;i+=256){
    pb += ws[OFF_FPART+i];
    ps += ws[OFF_FPART+512+i];
    pc += ws[OFF_FPART+1024+i];
  }
  float pw = ws[OFF_SWP+tid], pe = ws[OFF_SEWP+tid];
  pb = wave_sum(pb); ps = wave_sum(ps); pc = wave_sum(pc);
  pw = wave_sum(pw); pe = wave_sum(pe);
  const int w = tid>>6;
  if((tid&63)==0){ sb[0][w]=pb; sb[1][w]=ps; sb[2][w]=pc; sb[3][w]=pw; sb[4][w]=pe; }
  __syncthreads();
  if(tid==0){
    const float bce = sb[0][0]+sb[0][1]+sb[0][2]+sb[0][3];
    const float sp  = sb[1][0]+sb[1][1]+sb[1][2]+sb[1][3];
    const float spc = sb[2][0]+sb[2][1]+sb[2][2]+sb[2][3];
    const float sw  = sb[3][0]+sb[3][1]+sb[3][2]+sb[3][3];
    const float sew = sb[4][0]+sb[4][1]+sb[4][2]+sb[4][3];
    const float loss_vel  = sew / fmaxf(sw, 1.0f);
    const float loss_surv = bce / 16384.0f;
    // sum(pi*cost_n) = spc * (-ln2/20)  since klog = -20*log2e*cost_n
    const float loss_tr = (spc * (-0.03465735902799726f)) / fmaxf(sp, 1e-8f);
    out[0] = loss_vel + loss_surv + 0.1f*loss_tr;
  }
}

extern "C" void kernel_launch(void* const* d_in, const int* in_sizes, int n_in,
                              void* d_out, int out_size, void* d_ws, size_t ws_size,
                              hipStream_t stream) {
  (void)in_sizes; (void)n_in; (void)out_size; (void)ws_size;
  const float* x0  = (const float*)d_in[0];
  const float* xgt = (const float*)d_in[1];
  const float* vp  = (const float*)d_in[2];
  const float* ap  = (const float*)d_in[3];
  const float* mxp = (const float*)d_in[5];   // t (d_in[4]) unused
  float* ws  = (float*)d_ws;
  float* out = (float*)d_out;

  k_prep<<<256, 64, 0, stream>>>(x0, xgt, vp, ap, mxp, ws);
  k_cmax<<<512, 512, 0, stream>>>(ws);
  k_lse<true,true><<<512, 512, 0, stream>>>(ws, 0);
  for(int p=1;p<10;p++){
    if(p&1) k_lse<false,false><<<512, 512, 0, stream>>>(ws, p);
    else    k_lse<true ,false><<<512, 512, 0, stream>>>(ws, p);
  }
  k_final<<<512, 512, 0, stream>>>(ap, ws);
  k_out<<<1, 256, 0, stream>>>(ws, out);
}